// Round 2
// baseline (227.831 us; speedup 1.0000x reference)
//
#include <hip/hip_runtime.h>

constexpr int kLtot = 1024, kC = 32, kB = 2;
constexpr int kG = 64;                 // chunks per chain
constexpr int kCL = kLtot / kG;        // 16 steps per chunk
constexpr int kNCH = kB * kC;          // 64 chains
constexpr int kNCK = kNCH * kG;        // 4096 chunks
// LDS geometry (floats): padded rows for conflict-free row reads/writes
constexpr int kRowF = 20;              // 16 used + 4 pad (80 B rows -> balanced bank groups)
constexpr int kMatF = 16 * kRowF;      // 320 floats per 16x16 real matrix
constexpr int kChkF = 2 * kMatF + 8;   // Ar + Ai + pad = 648 (dword%32==8 -> q bank spread)
constexpr int kSlotF = 4 * kChkF;      // 2592 floats per ring slot (4 chunks)
constexpr int kRing = 3;

// complex MAC over 4 packed elements: rac/iac += (a4 + i*b4) . (vr + i*vi)[kb..kb+3]
#define CMAC4(a4, b4, vr, vi, kb)                                                                   \
  do {                                                                                              \
    rac += (a4).x * (vr)[(kb) + 0] - (b4).x * (vi)[(kb) + 0];                                       \
    iac += (a4).x * (vi)[(kb) + 0] + (b4).x * (vr)[(kb) + 0];                                       \
    rac += (a4).y * (vr)[(kb) + 1] - (b4).y * (vi)[(kb) + 1];                                       \
    iac += (a4).y * (vi)[(kb) + 1] + (b4).y * (vr)[(kb) + 1];                                       \
    rac += (a4).z * (vr)[(kb) + 2] - (b4).z * (vi)[(kb) + 2];                                       \
    iac += (a4).z * (vi)[(kb) + 2] + (b4).z * (vr)[(kb) + 2];                                       \
    rac += (a4).w * (vr)[(kb) + 3] - (b4).w * (vi)[(kb) + 3];                                       \
    iac += (a4).w * (vi)[(kb) + 3] + (b4).w * (vr)[(kb) + 3];                                       \
  } while (0)

// ---------------- Phase 1: chunk transition P_g (column-owned, in-lane) + response v_g ----------
// 1 wave per block, 4 chunks per wave (4 consecutive c of same (b,g)). Lane (q = lane>>4, j = lane&15)
// owns full column j of chunk q's P (16 complex in regs) -> matmul needs NO cross-lane traffic.
// v_g handled row-wise: lane computes v_new[j] = A[j][:].v + x[j], then one 32-shuffle redistribute.
__global__ __launch_bounds__(64, 1) void pscan_phase1(
    const float* __restrict__ Ar, const float* __restrict__ Ai,
    const float* __restrict__ Xr, const float* __restrict__ Xi,
    float* __restrict__ Pg, float* __restrict__ Vg) {
  __shared__ __align__(16) float lds[kRing * kSlotF];
  const int lane = threadIdx.x;
  const int j = lane & 15, q = lane >> 4;
  const int w = blockIdx.x;
  const int b = w >> 9, g = (w >> 3) & 63, cg = w & 7;
  const int c = cg * 4 + q;
  const int chain = b * kC + c;
  const size_t ck = (size_t)chain * kG + g;
  const int t0 = g * kCL;

  const size_t aRow0 = ((size_t)(b * kLtot + t0) * kC + c) * 256 + (size_t)j * 16;
  const size_t xEl0  = ((size_t)(b * kLtot + t0) * kC + c) * 16 + j;
  const size_t aStep = (size_t)kC * 256;
  const size_t xStep = (size_t)kC * 16;

  float4 st[8];  // staged A row j of chunk q (Ar 4x float4, Ai 4x float4)
  auto loadA = [&](int t) {
    const float* pr = Ar + aRow0 + (size_t)t * aStep;
    const float* pi = Ai + aRow0 + (size_t)t * aStep;
#pragma unroll
    for (int kk = 0; kk < 4; ++kk) st[kk] = *(const float4*)(pr + kk * 4);
#pragma unroll
    for (int kk = 0; kk < 4; ++kk) st[4 + kk] = *(const float4*)(pi + kk * 4);
  };
  auto writeA = [&](int slot) {
    float* d = &lds[slot * kSlotF + q * kChkF + j * kRowF];
#pragma unroll
    for (int kk = 0; kk < 4; ++kk) *(float4*)(d + kk * 4) = st[kk];
#pragma unroll
    for (int kk = 0; kk < 4; ++kk) *(float4*)(d + kMatF + kk * 4) = st[4 + kk];
  };

  // prologue: slots 0,1 filled; A(2) pending in regs
  loadA(0); writeA(0);
  loadA(1); writeA(1);
  loadA(2);
  float xrC = Xr[xEl0], xiC = Xi[xEl0];
  float xrN = Xr[xEl0 + xStep], xiN = Xi[xEl0 + xStep];

  float pre[16], pim[16], vre[16], vim[16];
#pragma unroll
  for (int i = 0; i < 16; ++i) {
    pre[i] = (i == j) ? 1.f : 0.f;  // P = I
    pim[i] = 0.f; vre[i] = 0.f; vim[i] = 0.f;
  }
  float wr = 0.f, wi = 0.f;  // lane's own v[j]

  for (int t = 0; t < kCL; ++t) {
    const float* base = &lds[(t % kRing) * kSlotF + q * kChkF];

    // ---- v: row-j dot (in-lane) ----
    {
      const float* rr = base + j * kRowF;
      const float* ri = rr + kMatF;
      float rac = xrC, iac = xiC;
#pragma unroll
      for (int kk = 0; kk < 4; ++kk) {
        const float4 a4 = *(const float4*)(rr + kk * 4);
        const float4 b4 = *(const float4*)(ri + kk * 4);
        CMAC4(a4, b4, vre, vim, 4 * kk);
      }
      wr = rac; wi = iac;
    }
    // redistribute v (single round, hides under the matmul below)
#pragma unroll
    for (int k = 0; k < 16; ++k) {
      vre[k] = __shfl(wr, (lane & 48) | k);
      vim[k] = __shfl(wi, (lane & 48) | k);
    }

    // ---- P column update: np[:] = A . p[:] (fully in-lane, rows broadcast from LDS) ----
    float npr[16], npi[16];
#pragma unroll
    for (int i = 0; i < 16; ++i) {
      const float* rr = base + i * kRowF;
      const float* ri = rr + kMatF;
      float rac = 0.f, iac = 0.f;
#pragma unroll
      for (int kk = 0; kk < 4; ++kk) {
        const float4 a4 = *(const float4*)(rr + kk * 4);
        const float4 b4 = *(const float4*)(ri + kk * 4);
        CMAC4(a4, b4, pre, pim, 4 * kk);
      }
      npr[i] = rac; npi[i] = iac;
    }
#pragma unroll
    for (int i = 0; i < 16; ++i) { pre[i] = npr[i]; pim[i] = npi[i]; }

    // ---- stage pipeline: write A(t+2) (in regs) to its slot, fetch A(t+3) ----
    writeA((t + 2) % kRing);
    const int tl = (t + 3 < kCL) ? (t + 3) : (kCL - 1);
    loadA(tl);
    xrC = xrN; xiC = xiN;
    const int tx = (t + 2 < kCL) ? (t + 2) : (kCL - 1);
    xrN = Xr[xEl0 + (size_t)tx * xStep];
    xiN = Xi[xEl0 + (size_t)tx * xStep];
  }

  // store P column-major: Pg[ck][col j][i]{re,im} -> 128B contiguous per lane
  float* pd = Pg + ck * 512 + (size_t)j * 32;
#pragma unroll
  for (int kk = 0; kk < 8; ++kk) {
    float4 o;
    o.x = pre[2 * kk]; o.y = pim[2 * kk];
    o.z = pre[2 * kk + 1]; o.w = pim[2 * kk + 1];
    *(float4*)(pd + kk * 4) = o;
  }
  *(float2*)(Vg + ck * 32 + (size_t)j * 2) = make_float2(wr, wi);
}

// ---------------- Phase 2: carry scan over chunks (row-owned dot + 1 shuffle round) -------------
// 16 blocks x 1 wave; wave handles 4 chains. Lane (q,j): in-lane dot with row j of P_g, y replicated.
__global__ __launch_bounds__(64, 1) void pscan_phase2(
    const float* __restrict__ Pg, const float* __restrict__ Vg, float* __restrict__ Sg) {
  const int lane = threadIdx.x;
  const int j = lane & 15, q = lane >> 4;
  const int chain = blockIdx.x * 4 + q;

  float yre[16], yim[16];
#pragma unroll
  for (int i = 0; i < 16; ++i) { yre[i] = 0.f; yim[i] = 0.f; }
  float wr = 0.f, wi = 0.f;  // lane's own y[j] (state entering current chunk)

  float prC[16], piC[16]; float2 vC;
  auto loadPV = [&](int gg, float* pr, float* pi, float2& v) {
    const size_t ckk = (size_t)chain * kG + gg;
    const float* pb = Pg + ckk * 512 + (size_t)j * 2;
#pragma unroll
    for (int k = 0; k < 16; ++k) {
      const float2 t = *(const float2*)(pb + k * 32);  // P[j][k] from column-major store
      pr[k] = t.x; pi[k] = t.y;
    }
    v = *(const float2*)(Vg + ckk * 32 + (size_t)j * 2);
  };
  loadPV(0, prC, piC, vC);

  for (int g = 0; g < kG; ++g) {
    float prN[16], piN[16]; float2 vN;
    const int gn = (g + 1 < kG) ? (g + 1) : (kG - 1);
    loadPV(gn, prN, piN, vN);

    const size_t ck = (size_t)chain * kG + g;
    *(float2*)(Sg + ck * 32 + (size_t)j * 2) = make_float2(wr, wi);  // S_{g-1}

    float rac = vC.x, iac = vC.y;
#pragma unroll
    for (int k = 0; k < 16; ++k) {
      rac += prC[k] * yre[k] - piC[k] * yim[k];
      iac += prC[k] * yim[k] + piC[k] * yre[k];
    }
    wr = rac; wi = iac;
#pragma unroll
    for (int k = 0; k < 16; ++k) {
      yre[k] = __shfl(wr, (lane & 48) | k);
      yim[k] = __shfl(wi, (lane & 48) | k);
    }
#pragma unroll
    for (int k = 0; k < 16; ++k) { prC[k] = prN[k]; piC[k] = piN[k]; }
    vC = vN;
  }
}

// ---------------- Phase 3: replay chunks from carries (row-owned, no LDS, reg double-buffer) ----
__global__ __launch_bounds__(64, 1) void pscan_phase3(
    const float* __restrict__ Ar, const float* __restrict__ Ai,
    const float* __restrict__ Xr, const float* __restrict__ Xi,
    const float* __restrict__ Sg, float* __restrict__ out) {
  const int lane = threadIdx.x;
  const int j = lane & 15, q = lane >> 4;
  const int w = blockIdx.x;
  const int b = w >> 9, g = (w >> 3) & 63, cg = w & 7;
  const int c = cg * 4 + q;
  const int chain = b * kC + c;
  const size_t ck = (size_t)chain * kG + g;
  const int t0 = g * kCL;

  const size_t aRow0 = ((size_t)(b * kLtot + t0) * kC + c) * 256 + (size_t)j * 16;
  const size_t xEl0  = ((size_t)(b * kLtot + t0) * kC + c) * 16 + j;
  const size_t aStep = (size_t)kC * 256, xStep = (size_t)kC * 16;
  float* outB = out + ((size_t)(b * kLtot + t0) * kC + c) * 32 + (size_t)j * 2;

  float yre[16], yim[16];
  {
    const float* sb = Sg + ck * 32;
#pragma unroll
    for (int kk = 0; kk < 8; ++kk) {
      const float4 t = *(const float4*)(sb + kk * 4);
      yre[2 * kk] = t.x; yim[2 * kk] = t.y;
      yre[2 * kk + 1] = t.z; yim[2 * kk + 1] = t.w;
    }
  }

  float4 aC[8], aN[8];
  auto loadArow = [&](int t, float4* d) {
    const float* pr = Ar + aRow0 + (size_t)t * aStep;
    const float* pi = Ai + aRow0 + (size_t)t * aStep;
#pragma unroll
    for (int kk = 0; kk < 4; ++kk) d[kk] = *(const float4*)(pr + kk * 4);
#pragma unroll
    for (int kk = 0; kk < 4; ++kk) d[4 + kk] = *(const float4*)(pi + kk * 4);
  };
  loadArow(0, aC);
  loadArow(1, aN);
  float xrC = Xr[xEl0], xiC = Xi[xEl0];
  float xrN = Xr[xEl0 + xStep], xiN = Xi[xEl0 + xStep];

  for (int t = 0; t < kCL; ++t) {
    float rac = xrC, iac = xiC;
#pragma unroll
    for (int kk = 0; kk < 4; ++kk) {
      const float4 a4 = aC[kk];
      const float4 b4 = aC[4 + kk];
      CMAC4(a4, b4, yre, yim, 4 * kk);
    }
    // store own element Y[t][j] (coalesced 512B per step across the wave)
    *(float2*)(outB + (size_t)t * (kC * 32)) = make_float2(rac, iac);
    // redistribute y_new to all lanes of this chunk (single round)
#pragma unroll
    for (int k = 0; k < 16; ++k) {
      yre[k] = __shfl(rac, (lane & 48) | k);
      yim[k] = __shfl(iac, (lane & 48) | k);
    }
    // rotate prefetch buffers
#pragma unroll
    for (int kk = 0; kk < 8; ++kk) aC[kk] = aN[kk];
    const int tn = (t + 2 < kCL) ? (t + 2) : (kCL - 1);
    loadArow(tn, aN);
    xrC = xrN; xiC = xiN;
    xrN = Xr[xEl0 + (size_t)tn * xStep];
    xiN = Xi[xEl0 + (size_t)tn * xStep];
  }
}

extern "C" void kernel_launch(void* const* d_in, const int* in_sizes, int n_in,
                              void* d_out, int out_size, void* d_ws, size_t ws_size,
                              hipStream_t stream) {
  const float* Ar = (const float*)d_in[0];
  const float* Ai = (const float*)d_in[1];
  const float* Xr = (const float*)d_in[2];
  const float* Xi = (const float*)d_in[3];
  // Workspace: Pg 8MB + Vg 512KB + Sg 512KB = 9MB
  float* Pg = (float*)d_ws;
  float* Vg = Pg + (size_t)kNCK * 512;
  float* Sg = Vg + (size_t)kNCK * 32;

  pscan_phase1<<<kNCK / 4, 64, 0, stream>>>(Ar, Ai, Xr, Xi, Pg, Vg);
  pscan_phase2<<<kNCH / 4, 64, 0, stream>>>(Pg, Vg, Sg);
  pscan_phase3<<<kNCK / 4, 64, 0, stream>>>(Ar, Ai, Xr, Xi, Sg, (float*)d_out);
}

// Round 3
// 148.273 us; speedup vs baseline: 1.5366x; 1.5366x over previous
//
#include <hip/hip_runtime.h>

#define DEVFN static __device__ __forceinline__

constexpr int kLtot = 1024, kC = 32, kB = 2;
constexpr int kG = 64;                 // chunks per chain
constexpr int kCL = kLtot / kG;        // 16 steps per chunk
constexpr int kNCH = kB * kC;          // 64 chains
constexpr int kNCK = kNCH * kG;        // 4096 chunks

// phase1 per-wave LDS: two 2048B A-slots (ring) + 18x144B pbuf (P bounce rows 0-15, v row 16, v dump 17)
constexpr int kSlotB = 2048;
constexpr int kPbufB = 18 * 144;       // 2592
constexpr int kWaveB = 2 * kSlotB + kPbufB;  // 6688 (16B aligned)

typedef int v2i __attribute__((ext_vector_type(2)));

DEVFN void gload16(const void* g, void* l) {
  __builtin_amdgcn_global_load_lds((const __attribute__((address_space(1))) void*)g,
                                   (__attribute__((address_space(3))) void*)l, 16, 0, 0);
}

// xor-16 pair sum via ds_swizzle (proven primitive), xor-32 via permlane32_swap sum-trick
DEVFN float redpair16(float x) {
  return x + __int_as_float(__builtin_amdgcn_ds_swizzle(__float_as_int(x), 0x401F));
}
DEVFN float redpair32(float x) {
#if __has_builtin(__builtin_amdgcn_permlane32_swap)
  v2i r = __builtin_amdgcn_permlane32_swap(__float_as_int(x), __float_as_int(x), false, false);
  return __int_as_float(r.x) + __int_as_float(r.y);
#else
  return x + __shfl_xor(x, 32);
#endif
}
DEVFN float redq(float x) { return redpair32(redpair16(x)); }  // sum over the 4 b-partners

DEVFN float sel4(float x0, float x1, float x2, float x3, int b) {
  float lo = (b & 1) ? x1 : x0;
  float hi = (b & 1) ? x3 : x2;
  return (b & 2) ? hi : lo;
}

// ---------------- Phase 1: chunk transition P_g + response v_g ----------------
// 1 chunk per wave, 4 waves per block. Lane (kq = k-quad, ka = i-interleave, kc = j-quad):
//   partials np[ka+4r][4kc+jj] over k in [4kq,4kq+4); reduce over kq (swizzle16 + permlane32);
//   p redistributed via per-wave LDS transpose bounce. v tracked as row jv = 4kc+ka.
__global__ __launch_bounds__(256, 4) void pscan_phase1(
    const float* __restrict__ Ar, const float* __restrict__ Ai,
    const float* __restrict__ Xr, const float* __restrict__ Xi,
    float* __restrict__ Pg, float* __restrict__ Vg) {
  __shared__ __align__(16) float ldsF[4 * (kWaveB / 4)];
  const int lane = threadIdx.x & 63;
  const int wid = threadIdx.x >> 6;
  const int kq = lane >> 4, ka = (lane >> 2) & 3, kc = lane & 3;
  const int jv = 4 * kc + ka;

  const int ck = blockIdx.x * 4 + wid;
  const int chain = ck >> 6, g = ck & 63;
  const int bb = chain >> 5, cc = chain & 31;
  const int t0 = g * kCL;

  char* ldsW = (char*)ldsF + wid * kWaveB;
  char* pbase = ldsW + 2 * kSlotB;
  const int laneA = ka * 64 + kq * 16;
  const int laneAv = laneA + kc * 256;

  const size_t aBase = ((size_t)(bb * kLtot + t0) * kC + cc) * 256;
  const size_t xBase = ((size_t)(bb * kLtot + t0) * kC + cc) * 16 + jv;
  const float* arPtr = Ar + aBase + (size_t)lane * 4;
  const float* aiPtr = Ai + aBase + (size_t)lane * 4;
  const float* xrPtr = Xr + xBase;
  const float* xiPtr = Xi + xBase;

  // pbuf addresses (all 16B-multiples except v float2)
  char* wA = pbase + (ka + 4 * kq) * 144 + kc * 32;           // write row ka+4kq, quad kc
  const char* rA = pbase + (4 * kq) * 144 + kc * 32;          // read rows 4kq+kk
  char* vwA = pbase + ((kq == 0) ? 2304 : 2448) + jv * 8;     // v write (others -> dump row)
  const char* vrA = pbase + 2304 + kq * 32;                   // v read slice

  float xrP[2], xiP[2];
  auto issueStep = [&](int t) {
    const size_t ao = (size_t)t * (kC * 256);
    char* sd = ldsW + (t & 1) * kSlotB;
    gload16(arPtr + ao, sd);
    gload16(aiPtr + ao, sd + 1024);
    xrP[t & 1] = xrPtr[(size_t)t * (kC * 16)];
    xiP[t & 1] = xiPtr[(size_t)t * (kC * 16)];
  };

  // prologue: steps 0 and 1 in flight (4 vmem ops each, order-stable groups)
  issueStep(0);
  asm volatile("" ::: "memory");
  issueStep(1);
  asm volatile("" ::: "memory");

  float prk[4][4], pik[4][4];   // p[kk][jj] = P[4kq+kk][4kc+jj]
  float npr[4][4], npi[4][4];   // np[r][jj] = P_new[ka+4r][4kc+jj]
  float vre[4], vim[4];         // v[4kq+kk]
  float vnr = 0.f, vni = 0.f;
#pragma unroll
  for (int kk = 0; kk < 4; ++kk) {
    vre[kk] = 0.f; vim[kk] = 0.f;
#pragma unroll
    for (int jj = 0; jj < 4; ++jj) {
      prk[kk][jj] = ((4 * kq + kk) == (4 * kc + jj)) ? 1.f : 0.f;  // P = I
      pik[kk][jj] = 0.f;
    }
  }

  auto stepCompute = [&](int t) {
    const char* sb = ldsW + (t & 1) * kSlotB;
    const char* sbl = sb + laneA;
#pragma unroll
    for (int r = 0; r < 4; ++r) {
      const float4 a4 = *(const float4*)(sbl + r * 256);
      const float4 b4 = *(const float4*)(sbl + 1024 + r * 256);
#pragma unroll
      for (int jj = 0; jj < 4; ++jj) {
        float nr = a4.x * prk[0][jj] - b4.x * pik[0][jj];
        float ni = a4.x * pik[0][jj] + b4.x * prk[0][jj];
        nr += a4.y * prk[1][jj] - b4.y * pik[1][jj];
        ni += a4.y * pik[1][jj] + b4.y * prk[1][jj];
        nr += a4.z * prk[2][jj] - b4.z * pik[2][jj];
        ni += a4.z * pik[2][jj] + b4.z * prk[2][jj];
        nr += a4.w * prk[3][jj] - b4.w * pik[3][jj];
        ni += a4.w * pik[3][jj] + b4.w * prk[3][jj];
        npr[r][jj] = nr; npi[r][jj] = ni;
      }
    }
    // v partial: row jv, own k-slice
    {
      const float4 a4 = *(const float4*)(sb + laneAv);
      const float4 b4 = *(const float4*)(sb + laneAv + 1024);
      float pr = a4.x * vre[0] - b4.x * vim[0];
      float pi = a4.x * vim[0] + b4.x * vre[0];
      pr += a4.y * vre[1] - b4.y * vim[1];  pi += a4.y * vim[1] + b4.y * vre[1];
      pr += a4.z * vre[2] - b4.z * vim[2];  pi += a4.z * vim[2] + b4.z * vre[2];
      pr += a4.w * vre[3] - b4.w * vim[3];  pi += a4.w * vim[3] + b4.w * vre[3];
      pr = redq(pr); pi = redq(pi);
      vnr = pr + xrP[t & 1];
      vni = pi + xiP[t & 1];
    }
    // reduce np over the 4 k-quads
#pragma unroll
    for (int r = 0; r < 4; ++r)
#pragma unroll
      for (int jj = 0; jj < 4; ++jj) {
        npr[r][jj] = redq(npr[r][jj]);
        npi[r][jj] = redq(npi[r][jj]);
      }
  };

  auto stepBounce = [&]() {
#pragma unroll
    for (int u = 0; u < 2; ++u) {
      float4 w;
      w.x = sel4(npr[0][2 * u], npr[1][2 * u], npr[2][2 * u], npr[3][2 * u], kq);
      w.y = sel4(npi[0][2 * u], npi[1][2 * u], npi[2][2 * u], npi[3][2 * u], kq);
      w.z = sel4(npr[0][2 * u + 1], npr[1][2 * u + 1], npr[2][2 * u + 1], npr[3][2 * u + 1], kq);
      w.w = sel4(npi[0][2 * u + 1], npi[1][2 * u + 1], npi[2][2 * u + 1], npi[3][2 * u + 1], kq);
      *(float4*)(wA + u * 16) = w;
    }
    *(float2*)vwA = make_float2(vnr, vni);
    asm volatile("s_waitcnt lgkmcnt(0)" ::: "memory");
#pragma unroll
    for (int kk = 0; kk < 4; ++kk) {
      const float4 q0 = *(const float4*)(rA + kk * 144);
      const float4 q1 = *(const float4*)(rA + kk * 144 + 16);
      prk[kk][0] = q0.x; pik[kk][0] = q0.y; prk[kk][1] = q0.z; pik[kk][1] = q0.w;
      prk[kk][2] = q1.x; pik[kk][2] = q1.y; prk[kk][3] = q1.z; pik[kk][3] = q1.w;
    }
    const float4 v0 = *(const float4*)(vrA);
    const float4 v1 = *(const float4*)(vrA + 16);
    vre[0] = v0.x; vim[0] = v0.y; vre[1] = v0.z; vim[1] = v0.w;
    vre[2] = v1.x; vim[2] = v1.y; vre[3] = v1.z; vim[3] = v1.w;
  };

#pragma unroll 2
  for (int t = 0; t < kCL - 2; ++t) {
    asm volatile("s_waitcnt vmcnt(4)" ::: "memory");
    stepCompute(t);
    stepBounce();
    issueStep(t + 2);
  }
  asm volatile("s_waitcnt vmcnt(4)" ::: "memory");
  stepCompute(kCL - 2);
  stepBounce();
  asm volatile("s_waitcnt vmcnt(0)" ::: "memory");
  stepCompute(kCL - 1);

  // store P_g (row-major [i][k] float2) and v_g from the kq==0 lanes
  if (kq == 0) {
    float* pd = Pg + (size_t)ck * 512;
#pragma unroll
    for (int r = 0; r < 4; ++r) {
#pragma unroll
      for (int u = 0; u < 2; ++u) {
        float4 o;
        o.x = npr[r][2 * u];     o.y = npi[r][2 * u];
        o.z = npr[r][2 * u + 1]; o.w = npi[r][2 * u + 1];
        *(float4*)(pd + (ka + 4 * r) * 32 + 8 * kc + 4 * u) = o;
      }
    }
    *(float2*)(Vg + (size_t)ck * 32 + jv * 2) = make_float2(vnr, vni);
  }
}

// ---------------- Phase 2: sequential carry scan (1 chain per block) ----------------
__global__ __launch_bounds__(64, 1) void pscan_phase2(
    const float* __restrict__ Pg, const float* __restrict__ Vg, float* __restrict__ Sg) {
  __shared__ __align__(16) float ybuf[64];
  const int lane = threadIdx.x;
  const int kq = lane >> 4, ka = (lane >> 2) & 3, kc = lane & 3;
  const int iv = 4 * kc + ka;
  const int chain = blockIdx.x;

  const float* pB = Pg + (size_t)chain * kG * 512 + (size_t)iv * 32 + 8 * kq;
  const float* vB = Vg + (size_t)chain * kG * 32 + iv * 2;
  float* sB = Sg + (size_t)chain * kG * 32 + iv * 2;
  float* ywA = (kq == 0) ? (ybuf + iv * 2) : (ybuf + 32 + iv * 2);

  float4 Pc0 = *(const float4*)(pB);
  float4 Pc1 = *(const float4*)(pB + 4);
  float2 vc = *(const float2*)(vB);

  float ysr[4] = {0, 0, 0, 0}, ysi[4] = {0, 0, 0, 0};
  float yvr = 0.f, yvi = 0.f;

  for (int g = 0; g < kG; ++g) {
    const int gn = (g + 1 < kG) ? (g + 1) : g;
    const float4 Pn0 = *(const float4*)(pB + (size_t)gn * 512);
    const float4 Pn1 = *(const float4*)(pB + (size_t)gn * 512 + 4);
    const float2 vn = *(const float2*)(vB + (size_t)gn * 32);

    if (kq == 0) *(float2*)(sB + (size_t)g * 32) = make_float2(yvr, yvi);  // S_{g-1}

    float tr = Pc0.x * ysr[0] - Pc0.y * ysi[0] + Pc0.z * ysr[1] - Pc0.w * ysi[1]
             + Pc1.x * ysr[2] - Pc1.y * ysi[2] + Pc1.z * ysr[3] - Pc1.w * ysi[3];
    float ti = Pc0.x * ysi[0] + Pc0.y * ysr[0] + Pc0.z * ysi[1] + Pc0.w * ysr[1]
             + Pc1.x * ysi[2] + Pc1.y * ysr[2] + Pc1.z * ysi[3] + Pc1.w * ysr[3];
    tr = redq(tr); ti = redq(ti);
    yvr = tr + vc.x;
    yvi = ti + vc.y;

    *(float2*)ywA = make_float2(yvr, yvi);
    asm volatile("s_waitcnt lgkmcnt(0)" ::: "memory");
    const float4 y0 = *(const float4*)(ybuf + 8 * kq);
    const float4 y1 = *(const float4*)(ybuf + 8 * kq + 4);
    ysr[0] = y0.x; ysi[0] = y0.y; ysr[1] = y0.z; ysi[1] = y0.w;
    ysr[2] = y1.x; ysi[2] = y1.y; ysr[3] = y1.z; ysi[3] = y1.w;

    Pc0 = Pn0; Pc1 = Pn1; vc = vn;
  }
}

// ---------------- Phase 3: replay chunks from carries (row-owned, reg double-buffer) ----
__global__ __launch_bounds__(64, 1) void pscan_phase3(
    const float* __restrict__ Ar, const float* __restrict__ Ai,
    const float* __restrict__ Xr, const float* __restrict__ Xi,
    const float* __restrict__ Sg, float* __restrict__ out) {
  const int lane = threadIdx.x;
  const int j = lane & 15, q = lane >> 4;
  const int w = blockIdx.x;
  const int b = w >> 9, g = (w >> 3) & 63, cg = w & 7;
  const int c = cg * 4 + q;
  const int chain = b * kC + c;
  const size_t ck = (size_t)chain * kG + g;
  const int t0 = g * kCL;

  const size_t aRow0 = ((size_t)(b * kLtot + t0) * kC + c) * 256 + (size_t)j * 16;
  const size_t xEl0  = ((size_t)(b * kLtot + t0) * kC + c) * 16 + j;
  const size_t aStep = (size_t)kC * 256, xStep = (size_t)kC * 16;
  float* outB = out + ((size_t)(b * kLtot + t0) * kC + c) * 32 + (size_t)j * 2;

  float yre[16], yim[16];
  {
    const float* sb = Sg + ck * 32;
#pragma unroll
    for (int kk = 0; kk < 8; ++kk) {
      const float4 t = *(const float4*)(sb + kk * 4);
      yre[2 * kk] = t.x; yim[2 * kk] = t.y;
      yre[2 * kk + 1] = t.z; yim[2 * kk + 1] = t.w;
    }
  }

  float4 aC[8], aN[8];
  auto loadArow = [&](int t, float4* d) {
    const float* pr = Ar + aRow0 + (size_t)t * aStep;
    const float* pi = Ai + aRow0 + (size_t)t * aStep;
#pragma unroll
    for (int kk = 0; kk < 4; ++kk) d[kk] = *(const float4*)(pr + kk * 4);
#pragma unroll
    for (int kk = 0; kk < 4; ++kk) d[4 + kk] = *(const float4*)(pi + kk * 4);
  };
  loadArow(0, aC);
  loadArow(1, aN);
  float xrC = Xr[xEl0], xiC = Xi[xEl0];
  float xrN = Xr[xEl0 + xStep], xiN = Xi[xEl0 + xStep];

  for (int t = 0; t < kCL; ++t) {
    float rac = xrC, iac = xiC;
#pragma unroll
    for (int kk = 0; kk < 4; ++kk) {
      const float4 a4 = aC[kk];
      const float4 b4 = aC[4 + kk];
      rac += a4.x * yre[4 * kk + 0] - b4.x * yim[4 * kk + 0];
      iac += a4.x * yim[4 * kk + 0] + b4.x * yre[4 * kk + 0];
      rac += a4.y * yre[4 * kk + 1] - b4.y * yim[4 * kk + 1];
      iac += a4.y * yim[4 * kk + 1] + b4.y * yre[4 * kk + 1];
      rac += a4.z * yre[4 * kk + 2] - b4.z * yim[4 * kk + 2];
      iac += a4.z * yim[4 * kk + 2] + b4.z * yre[4 * kk + 2];
      rac += a4.w * yre[4 * kk + 3] - b4.w * yim[4 * kk + 3];
      iac += a4.w * yim[4 * kk + 3] + b4.w * yre[4 * kk + 3];
    }
    *(float2*)(outB + (size_t)t * (kC * 32)) = make_float2(rac, iac);
#pragma unroll
    for (int k = 0; k < 16; ++k) {
      yre[k] = __shfl(rac, (lane & 48) | k);
      yim[k] = __shfl(iac, (lane & 48) | k);
    }
#pragma unroll
    for (int kk = 0; kk < 8; ++kk) aC[kk] = aN[kk];
    const int tn = (t + 2 < kCL) ? (t + 2) : (kCL - 1);
    loadArow(tn, aN);
    xrC = xrN; xiC = xiN;
    xrN = Xr[xEl0 + (size_t)tn * xStep];
    xiN = Xi[xEl0 + (size_t)tn * xStep];
  }
}

extern "C" void kernel_launch(void* const* d_in, const int* in_sizes, int n_in,
                              void* d_out, int out_size, void* d_ws, size_t ws_size,
                              hipStream_t stream) {
  const float* Ar = (const float*)d_in[0];
  const float* Ai = (const float*)d_in[1];
  const float* Xr = (const float*)d_in[2];
  const float* Xi = (const float*)d_in[3];
  // Workspace: Pg 8MB + Vg 512KB + Sg 512KB = 9MB
  float* Pg = (float*)d_ws;
  float* Vg = Pg + (size_t)kNCK * 512;
  float* Sg = Vg + (size_t)kNCK * 32;

  pscan_phase1<<<kNCK / 4, 256, 0, stream>>>(Ar, Ai, Xr, Xi, Pg, Vg);
  pscan_phase2<<<kNCH, 64, 0, stream>>>(Pg, Vg, Sg);
  pscan_phase3<<<kNCK / 4, 64, 0, stream>>>(Ar, Ai, Xr, Xi, Sg, (float*)d_out);
}

// Round 4
// 121.275 us; speedup vs baseline: 1.8786x; 1.2226x over previous
//
#include <hip/hip_runtime.h>

#define DEVFN static __device__ __forceinline__

constexpr int kLtot = 1024, kC = 32, kB = 2;
constexpr int kG = 64;                 // chunks per chain
constexpr int kCL = kLtot / kG;        // 16 steps per chunk
constexpr int kNCH = kB * kC;          // 64 chains
constexpr int kNCK = kNCH * kG;        // 4096 chunks

// phase1 per-wave LDS: two 2048B A-slots (ring) + 17x144B pbuf (P bounce rows 0-15, v row 16)
constexpr int kSlotB = 2048;
constexpr int kPbufB = 17 * 144;       // 2448
constexpr int kWaveB = 2 * kSlotB + kPbufB;  // 6544 (16B aligned)

typedef int v2i __attribute__((ext_vector_type(2)));

DEVFN void gload16(const void* g, void* l) {
  __builtin_amdgcn_global_load_lds((const __attribute__((address_space(1))) void*)g,
                                   (__attribute__((address_space(3))) void*)l, 16, 0, 0);
}

// xor-16 / xor-32 pair sums — pure VALU via permlane*_swap where available
DEVFN float redpair16(float x) {
#if __has_builtin(__builtin_amdgcn_permlane16_swap)
  v2i r = __builtin_amdgcn_permlane16_swap(__float_as_int(x), __float_as_int(x), false, false);
  return __int_as_float(r.x) + __int_as_float(r.y);
#else
  return x + __int_as_float(__builtin_amdgcn_ds_swizzle(__float_as_int(x), 0x401F));
#endif
}
DEVFN float redpair32(float x) {
#if __has_builtin(__builtin_amdgcn_permlane32_swap)
  v2i r = __builtin_amdgcn_permlane32_swap(__float_as_int(x), __float_as_int(x), false, false);
  return __int_as_float(r.x) + __int_as_float(r.y);
#else
  return x + __shfl_xor(x, 32);
#endif
}
DEVFN float redq(float x) { return redpair32(redpair16(x)); }  // sum over the 4 kq-partners

DEVFN float sel4(float x0, float x1, float x2, float x3, int b) {
  float lo = (b & 1) ? x1 : x0;
  float hi = (b & 1) ? x3 : x2;
  return (b & 2) ? hi : lo;
}

// ---------------- Phase 1: chunk transition P_g + response v_g ----------------
// 1 chunk per wave, 4 waves per block. Lane (kq, ka, kc): partials np[ka+4r][4kc+jj] over
// k in [4kq,4kq+4); reduce over kq via permlane16/32 (VALU); p redistributed via per-wave
// LDS transpose bounce. v tracked as row jv = 4kc+ka. P starts as A_0 (step 0 is free).
__global__ __launch_bounds__(256, 4) void pscan_phase1(
    const float* __restrict__ Ar, const float* __restrict__ Ai,
    const float* __restrict__ Xr, const float* __restrict__ Xi,
    float* __restrict__ Pg, float* __restrict__ Vg) {
  __shared__ __align__(16) float ldsF[4 * (kWaveB / 4)];
  const int lane = threadIdx.x & 63;
  const int wid = threadIdx.x >> 6;
  const int kq = lane >> 4, ka = (lane >> 2) & 3, kc = lane & 3;
  const int jv = 4 * kc + ka;

  const int ck = blockIdx.x * 4 + wid;
  const int chain = ck >> 6, g = ck & 63;
  const int bb = chain >> 5, cc = chain & 31;
  const int t0 = g * kCL;

  char* ldsW = (char*)ldsF + wid * kWaveB;
  char* pbase = ldsW + 2 * kSlotB;
  const int laneA = ka * 64 + kq * 16;
  const int laneAv = laneA + kc * 256;

  const size_t aBase = ((size_t)(bb * kLtot + t0) * kC + cc) * 256;
  const size_t xBase2 = ((size_t)(bb * kLtot + t0) * kC + cc) * 16;
  const float* arPtr = Ar + aBase + (size_t)lane * 4;
  const float* aiPtr = Ai + aBase + (size_t)lane * 4;
  const float* xrPtr = Xr + xBase2 + jv;
  const float* xiPtr = Xi + xBase2 + jv;

  char* wA = pbase + (ka + 4 * kq) * 144 + kc * 32;           // bounce write row ka+4kq, quad kc
  const char* rA = pbase + (4 * kq) * 144 + kc * 32;          // bounce read rows 4kq+kk
  char* vwA = pbase + 2304 + jv * 8;                          // v write (kq==0 lanes only)
  const char* vrA = pbase + 2304 + kq * 32;                   // v read slice

  float xrP[2], xiP[2];
  auto issueStep = [&](int t) {
    const size_t ao = (size_t)t * (kC * 256);
    char* sd = ldsW + (t & 1) * kSlotB;
    gload16(arPtr + ao, sd);
    gload16(aiPtr + ao, sd + 1024);
    xrP[t & 1] = xrPtr[(size_t)t * (kC * 16)];
    xiP[t & 1] = xiPtr[(size_t)t * (kC * 16)];
  };

  issueStep(0);
  asm volatile("" ::: "memory");
  issueStep(1);
  asm volatile("" ::: "memory");

  float prk[4][4], pik[4][4];   // p[kk][jj] = P[4kq+kk][4kc+jj]
  float npr[4][4], npi[4][4];   // np[r][jj] = P_new[ka+4r][4kc+jj]
  float vre[4], vim[4];         // v[4kq+kk]
  float vnr = 0.f, vni = 0.f;

  // ---- init: P = A_0, v = x_0 (skips the identity matmul) ----
  asm volatile("s_waitcnt vmcnt(4)" ::: "memory");  // slot 0 resident
  {
    const char* sb = ldsW;
#pragma unroll
    for (int kk = 0; kk < 4; ++kk) {
      const float4 a4 = *(const float4*)(sb + (4 * kq + kk) * 64 + kc * 16);
      const float4 b4 = *(const float4*)(sb + 1024 + (4 * kq + kk) * 64 + kc * 16);
      prk[kk][0] = a4.x; prk[kk][1] = a4.y; prk[kk][2] = a4.z; prk[kk][3] = a4.w;
      pik[kk][0] = b4.x; pik[kk][1] = b4.y; pik[kk][2] = b4.z; pik[kk][3] = b4.w;
    }
    const float* xr0 = Xr + xBase2;
    const float* xi0 = Xi + xBase2;
#pragma unroll
    for (int kk = 0; kk < 4; ++kk) {
      vre[kk] = xr0[4 * kq + kk];
      vim[kk] = xi0[4 * kq + kk];
    }
  }
  asm volatile("s_waitcnt lgkmcnt(0)" ::: "memory");  // slot-0 reads done before re-staging
  issueStep(2);
  asm volatile("" ::: "memory");

  auto stepCompute = [&](int t) {
    const char* sb = ldsW + (t & 1) * kSlotB;
    const char* sbl = sb + laneA;
#pragma unroll
    for (int r = 0; r < 4; ++r) {
      const float4 a4 = *(const float4*)(sbl + r * 256);
      const float4 b4 = *(const float4*)(sbl + 1024 + r * 256);
#pragma unroll
      for (int jj = 0; jj < 4; ++jj) {
        float nr = a4.x * prk[0][jj] - b4.x * pik[0][jj];
        float ni = a4.x * pik[0][jj] + b4.x * prk[0][jj];
        nr += a4.y * prk[1][jj] - b4.y * pik[1][jj];
        ni += a4.y * pik[1][jj] + b4.y * prk[1][jj];
        nr += a4.z * prk[2][jj] - b4.z * pik[2][jj];
        ni += a4.z * pik[2][jj] + b4.z * prk[2][jj];
        nr += a4.w * prk[3][jj] - b4.w * pik[3][jj];
        ni += a4.w * pik[3][jj] + b4.w * prk[3][jj];
        npr[r][jj] = nr; npi[r][jj] = ni;
      }
    }
    {
      const float4 a4 = *(const float4*)(sb + laneAv);
      const float4 b4 = *(const float4*)(sb + laneAv + 1024);
      float pr = a4.x * vre[0] - b4.x * vim[0];
      float pi = a4.x * vim[0] + b4.x * vre[0];
      pr += a4.y * vre[1] - b4.y * vim[1];  pi += a4.y * vim[1] + b4.y * vre[1];
      pr += a4.z * vre[2] - b4.z * vim[2];  pi += a4.z * vim[2] + b4.z * vre[2];
      pr += a4.w * vre[3] - b4.w * vim[3];  pi += a4.w * vim[3] + b4.w * vre[3];
      pr = redq(pr); pi = redq(pi);
      vnr = pr + xrP[t & 1];
      vni = pi + xiP[t & 1];
    }
#pragma unroll
    for (int r = 0; r < 4; ++r)
#pragma unroll
      for (int jj = 0; jj < 4; ++jj) {
        npr[r][jj] = redq(npr[r][jj]);
        npi[r][jj] = redq(npi[r][jj]);
      }
  };

  auto stepBounce = [&]() {
#pragma unroll
    for (int u = 0; u < 2; ++u) {
      float4 w;
      w.x = sel4(npr[0][2 * u], npr[1][2 * u], npr[2][2 * u], npr[3][2 * u], kq);
      w.y = sel4(npi[0][2 * u], npi[1][2 * u], npi[2][2 * u], npi[3][2 * u], kq);
      w.z = sel4(npr[0][2 * u + 1], npr[1][2 * u + 1], npr[2][2 * u + 1], npr[3][2 * u + 1], kq);
      w.w = sel4(npi[0][2 * u + 1], npi[1][2 * u + 1], npi[2][2 * u + 1], npi[3][2 * u + 1], kq);
      *(float4*)(wA + u * 16) = w;
    }
    if (kq == 0) *(float2*)vwA = make_float2(vnr, vni);
    asm volatile("s_waitcnt lgkmcnt(0)" ::: "memory");
#pragma unroll
    for (int kk = 0; kk < 4; ++kk) {
      const float4 q0 = *(const float4*)(rA + kk * 144);
      const float4 q1 = *(const float4*)(rA + kk * 144 + 16);
      prk[kk][0] = q0.x; pik[kk][0] = q0.y; prk[kk][1] = q0.z; pik[kk][1] = q0.w;
      prk[kk][2] = q1.x; pik[kk][2] = q1.y; prk[kk][3] = q1.z; pik[kk][3] = q1.w;
    }
    const float4 v0 = *(const float4*)(vrA);
    const float4 v1 = *(const float4*)(vrA + 16);
    vre[0] = v0.x; vim[0] = v0.y; vre[1] = v0.z; vim[1] = v0.w;
    vre[2] = v1.x; vim[2] = v1.y; vre[3] = v1.z; vim[3] = v1.w;
  };

#pragma unroll 2
  for (int t = 1; t < kCL - 2; ++t) {
    asm volatile("s_waitcnt vmcnt(4)" ::: "memory");
    stepCompute(t);
    stepBounce();
    issueStep(t + 2);
  }
  asm volatile("s_waitcnt vmcnt(4)" ::: "memory");
  stepCompute(kCL - 2);
  stepBounce();
  asm volatile("s_waitcnt vmcnt(0)" ::: "memory");
  stepCompute(kCL - 1);

  // store P_g (row-major [i][k] float2) and v_g from the kq==0 lanes
  if (kq == 0) {
    float* pd = Pg + (size_t)ck * 512;
#pragma unroll
    for (int r = 0; r < 4; ++r) {
#pragma unroll
      for (int u = 0; u < 2; ++u) {
        float4 o;
        o.x = npr[r][2 * u];     o.y = npi[r][2 * u];
        o.z = npr[r][2 * u + 1]; o.w = npi[r][2 * u + 1];
        *(float4*)(pd + (ka + 4 * r) * 32 + 8 * kc + 4 * u) = o;
      }
    }
    *(float2*)(Vg + (size_t)ck * 32 + jv * 2) = make_float2(vnr, vni);
  }
}

// ---------------- Phase 2: sequential carry scan (1 chain per wave, 64-lane matvec) ----------
// Lane (kq = lane>>4, i = lane&15): partial y_new[i] over k-quad kq; permlane reduce;
// shfl redistribute. Depth-4 register prefetch of P/v (statically indexed).
constexpr int kD2 = 4;
__global__ __launch_bounds__(64, 1) void pscan_phase2(
    const float* __restrict__ Pg, const float* __restrict__ Vg, float* __restrict__ Sg) {
  const int lane = threadIdx.x;
  const int kq = lane >> 4, i = lane & 15;
  const int chain = blockIdx.x;

  const float* pB = Pg + (size_t)chain * kG * 512 + (size_t)i * 32 + 8 * kq;
  const float* vB = Vg + (size_t)chain * kG * 32 + 2 * i;
  float* sB = Sg + (size_t)chain * kG * 32 + 2 * i;

  float4 bP0[kD2], bP1[kD2]; float2 bV[kD2];
#pragma unroll
  for (int d = 0; d < kD2; ++d) {
    bP0[d] = *(const float4*)(pB + (size_t)d * 512);
    bP1[d] = *(const float4*)(pB + (size_t)d * 512 + 4);
    bV[d] = *(const float2*)(vB + (size_t)d * 32);
  }

  float ykr[4] = {0, 0, 0, 0}, yki[4] = {0, 0, 0, 0};  // y[4kq+kk]
  float ynr = 0.f, yni = 0.f;                          // own y[i]

  for (int gg = 0; gg < kG; gg += kD2) {
#pragma unroll
    for (int d = 0; d < kD2; ++d) {
      if (kq == 0) *(float2*)(sB + (size_t)(gg + d) * 32) = make_float2(ynr, yni);  // S_{g-1}
      const float4 p0 = bP0[d], p1 = bP1[d];
      const float2 vv = bV[d];
      const int gn = gg + d + kD2;
      if (gn < kG) {
        bP0[d] = *(const float4*)(pB + (size_t)gn * 512);
        bP1[d] = *(const float4*)(pB + (size_t)gn * 512 + 4);
        bV[d] = *(const float2*)(vB + (size_t)gn * 32);
      }
      float tr = p0.x * ykr[0] - p0.y * yki[0] + p0.z * ykr[1] - p0.w * yki[1]
               + p1.x * ykr[2] - p1.y * yki[2] + p1.z * ykr[3] - p1.w * yki[3];
      float ti = p0.x * yki[0] + p0.y * ykr[0] + p0.z * yki[1] + p0.w * ykr[1]
               + p1.x * yki[2] + p1.y * ykr[2] + p1.z * yki[3] + p1.w * ykr[3];
      tr = redq(tr); ti = redq(ti);
      ynr = tr + vv.x;
      yni = ti + vv.y;
#pragma unroll
      for (int kk = 0; kk < 4; ++kk) {
        const int src = (lane & 48) | (4 * kq + kk);
        ykr[kk] = __shfl(ynr, src);
        yki[kk] = __shfl(yni, src);
      }
    }
  }
}

// ---------------- Phase 3: replay chunks from carries (64-lane matvec, 16 waves/CU) ----------
__global__ __launch_bounds__(256, 4) void pscan_phase3(
    const float* __restrict__ Ar, const float* __restrict__ Ai,
    const float* __restrict__ Xr, const float* __restrict__ Xi,
    const float* __restrict__ Sg, float* __restrict__ out) {
  const int lane = threadIdx.x & 63;
  const int wid = threadIdx.x >> 6;
  const int kq = lane >> 4, i = lane & 15;
  const int ck = blockIdx.x * 4 + wid;
  const int chain = ck >> 6, g = ck & 63;
  const int bb = chain >> 5, cc = chain & 31;
  const int t0 = g * kCL;

  const size_t aBase = ((size_t)(bb * kLtot + t0) * kC + cc) * 256 + (size_t)i * 16 + 4 * kq;
  const size_t xBase = ((size_t)(bb * kLtot + t0) * kC + cc) * 16 + i;
  const size_t aStep = (size_t)kC * 256, xStep = (size_t)kC * 16;
  float* outB = out + ((size_t)(bb * kLtot + t0) * kC + cc) * 32 + 2 * i;

  float ynr, yni, ykr[4], yki[4];
  {
    const float2 s = *(const float2*)(Sg + (size_t)ck * 32 + 2 * i);
    ynr = s.x; yni = s.y;
  }
#pragma unroll
  for (int kk = 0; kk < 4; ++kk) {
    const int src = (lane & 48) | (4 * kq + kk);
    ykr[kk] = __shfl(ynr, src);
    yki[kk] = __shfl(yni, src);
  }

  float4 aR[2], aI[2]; float2 xx[2];
  auto loadT = [&](int t, int s) {
    aR[s] = *(const float4*)(Ar + aBase + (size_t)t * aStep);
    aI[s] = *(const float4*)(Ai + aBase + (size_t)t * aStep);
    xx[s].x = Xr[xBase + (size_t)t * xStep];
    xx[s].y = Xi[xBase + (size_t)t * xStep];
  };
  loadT(0, 0);
  loadT(1, 1);

  for (int t = 0; t < kCL; ++t) {
    const int s = t & 1;
    const float4 a4 = aR[s], b4 = aI[s];
    const float2 xv = xx[s];
    float tr = a4.x * ykr[0] - b4.x * yki[0] + a4.y * ykr[1] - b4.y * yki[1]
             + a4.z * ykr[2] - b4.z * yki[2] + a4.w * ykr[3] - b4.w * yki[3];
    float ti = a4.x * yki[0] + b4.x * ykr[0] + a4.y * yki[1] + b4.y * ykr[1]
             + a4.z * yki[2] + b4.z * ykr[2] + a4.w * yki[3] + b4.w * ykr[3];
    tr = redq(tr); ti = redq(ti);
    ynr = tr + xv.x;
    yni = ti + xv.y;
    if (kq == 0) *(float2*)(outB + (size_t)t * (kC * 32)) = make_float2(ynr, yni);
    const int tn = t + 2;
    if (tn < kCL) loadT(tn, s);
#pragma unroll
    for (int kk = 0; kk < 4; ++kk) {
      const int src = (lane & 48) | (4 * kq + kk);
      ykr[kk] = __shfl(ynr, src);
      yki[kk] = __shfl(yni, src);
    }
  }
}

extern "C" void kernel_launch(void* const* d_in, const int* in_sizes, int n_in,
                              void* d_out, int out_size, void* d_ws, size_t ws_size,
                              hipStream_t stream) {
  const float* Ar = (const float*)d_in[0];
  const float* Ai = (const float*)d_in[1];
  const float* Xr = (const float*)d_in[2];
  const float* Xi = (const float*)d_in[3];
  // Workspace: Pg 8MB + Vg 512KB + Sg 512KB = 9MB
  float* Pg = (float*)d_ws;
  float* Vg = Pg + (size_t)kNCK * 512;
  float* Sg = Vg + (size_t)kNCK * 32;

  pscan_phase1<<<kNCK / 4, 256, 0, stream>>>(Ar, Ai, Xr, Xi, Pg, Vg);
  pscan_phase2<<<kNCH, 64, 0, stream>>>(Pg, Vg, Sg);
  pscan_phase3<<<kNCK / 4, 256, 0, stream>>>(Ar, Ai, Xr, Xi, Sg, (float*)d_out);
}